// Round 2
// baseline (558.667 us; speedup 1.0000x reference)
//
#include <hip/hip_runtime.h>
#include <math.h>

// MambaForecaster: B=16, L=2048, Dm=64, NL=4, ED=128, N=16, R=4, DC=4
#define B_   16
#define L_   2048
#define DM   64
#define NL_  4
#define ED_  128
#define NS   16
#define RK   4
#define BL   (B_*L_)          // 32768 rows
#define CHUNKS 64
#define CHLEN  (L_/CHUNKS)    // 32

// ---------------- RMSNorm: 16 lanes per row of 64 ----------------
__global__ __launch_bounds__(256) void rmsnorm_k(const float* __restrict__ X,
    const float* __restrict__ w, float* __restrict__ XN)
{
  int tid = threadIdx.x;
  int row = blockIdx.x * 16 + (tid >> 4);
  int q = tid & 15;
  float4 v = *(const float4*)(X + (size_t)row * 64 + q * 4);
  float ss = v.x*v.x + v.y*v.y + v.z*v.z + v.w*v.w;
  ss += __shfl_xor(ss, 1, 16);
  ss += __shfl_xor(ss, 2, 16);
  ss += __shfl_xor(ss, 4, 16);
  ss += __shfl_xor(ss, 8, 16);
  float sc = rsqrtf(ss * (1.0f/64.0f) + 1e-5f);
  float4 wv = *(const float4*)(w + q * 4);
  float4 o;
  o.x = v.x*sc*wv.x; o.y = v.y*sc*wv.y; o.z = v.z*sc*wv.z; o.w = v.w*sc*wv.w;
  *(float4*)(XN + (size_t)row * 64 + q * 4) = o;
}

// ---------------- GEMM1: xz = xn @ in_w^T  (M=BL, K=64, N=256; grid.y = col half)
__global__ __launch_bounds__(256) void gemm_in_k(const float* __restrict__ XN,
    const float* __restrict__ W, float* __restrict__ XZ)
{
  __shared__ float4 sX[32][16];    // 32 rows x 64 K           (8 KB)
  __shared__ float4 sW[16][128];   // [k4][c], 128 cols half   (32 KB)
  int tid = threadIdx.x;
  int row0 = blockIdx.x * 32;
  const float* Wh = W + (size_t)blockIdx.y * 128 * 64;
  for (int i = tid; i < 32 * 16; i += 256) {
    int r = i >> 4, k4 = i & 15;
    sX[r][k4] = *(const float4*)(XN + (size_t)(row0 + r) * 64 + k4 * 4);
  }
  for (int i = tid; i < 128 * 16; i += 256) {
    int c = i >> 4, k4 = i & 15;
    sW[k4][c] = *(const float4*)(Wh + (size_t)c * 64 + k4 * 4);
  }
  __syncthreads();
  int rg = tid >> 4;   // rows 2rg, 2rg+1
  int cg = tid & 15;   // cols cg + 16j, j<8
  float acc0[8], acc1[8];
#pragma unroll
  for (int j = 0; j < 8; j++) { acc0[j] = 0.f; acc1[j] = 0.f; }
  for (int k4 = 0; k4 < 16; k4++) {
    float4 x0 = sX[2*rg][k4];
    float4 x1 = sX[2*rg+1][k4];
#pragma unroll
    for (int j = 0; j < 8; j++) {
      float4 wv = sW[k4][cg + 16*j];
      acc0[j] = fmaf(x0.x,wv.x, fmaf(x0.y,wv.y, fmaf(x0.z,wv.z, fmaf(x0.w,wv.w, acc0[j]))));
      acc1[j] = fmaf(x1.x,wv.x, fmaf(x1.y,wv.y, fmaf(x1.z,wv.z, fmaf(x1.w,wv.w, acc1[j]))));
    }
  }
#pragma unroll
  for (int j = 0; j < 8; j++) {
    int c = blockIdx.y * 128 + cg + 16*j;
    XZ[(size_t)(row0 + 2*rg    ) * 256 + c] = acc0[j];
    XZ[(size_t)(row0 + 2*rg + 1) * 256 + c] = acc1[j];
  }
}

// ---------------- depthwise causal conv(DC=4) + silu ----------------
__global__ __launch_bounds__(256) void conv_silu_k(const float* __restrict__ XZ,
    const float* __restrict__ cw, const float* __restrict__ cb, float* __restrict__ XI)
{
  int idx = blockIdx.x * 256 + threadIdx.x;   // BL*128
  int e = idx & 127;
  int bl = idx >> 7;
  int l = bl & (L_ - 1);
  float4 w = *(const float4*)(cw + e * 4);
  const float* base = XZ + (size_t)bl * 256 + e;
  float acc = cb[e];
  float x3 = (l >= 3) ? base[-3*256] : 0.f;
  float x2 = (l >= 2) ? base[-2*256] : 0.f;
  float x1 = (l >= 1) ? base[-1*256] : 0.f;
  float x0 = base[0];
  acc = fmaf(x3, w.x, acc);
  acc = fmaf(x2, w.y, acc);
  acc = fmaf(x1, w.z, acc);
  acc = fmaf(x0, w.w, acc);
  float s = acc / (1.f + __expf(-acc));   // silu
  XI[idx] = s;
}

// ---------------- GEMM2: dbc = xi @ xp_w^T  (M=BL, K=128, N=36) ----------------
__global__ __launch_bounds__(256) void gemm_dbc_k(const float* __restrict__ XI,
    const float* __restrict__ W, float* __restrict__ DBC)
{
  __shared__ float4 sX[64][32];   // 64 rows x 128 K (32 KB)
  __shared__ float4 sW[32][40];   // [k4][f], f padded 36->40 (20 KB)
  int tid = threadIdx.x;
  int row0 = blockIdx.x * 64;
  for (int i = tid; i < 64 * 32; i += 256) {
    int r = i >> 5, k4 = i & 31;
    sX[r][k4] = *(const float4*)(XI + (size_t)(row0 + r) * 128 + k4 * 4);
  }
  for (int i = tid; i < 36 * 32; i += 256) {
    int f = i >> 5, k4 = i & 31;
    sW[k4][f] = *(const float4*)(W + (size_t)f * 128 + k4 * 4);
  }
  __syncthreads();
  int rg = tid >> 3;  // rows 2rg, 2rg+1
  int cg = tid & 7;   // cols cg + 8j, j<5 (valid if <36)
  float acc0[5], acc1[5];
#pragma unroll
  for (int j = 0; j < 5; j++) { acc0[j] = 0.f; acc1[j] = 0.f; }
  for (int k4 = 0; k4 < 32; k4++) {
    float4 x0 = sX[2*rg][k4];
    float4 x1 = sX[2*rg+1][k4];
#pragma unroll
    for (int j = 0; j < 5; j++) {
      float4 wv = sW[k4][cg + 8*j];   // padded rows read garbage, never stored
      acc0[j] = fmaf(x0.x,wv.x, fmaf(x0.y,wv.y, fmaf(x0.z,wv.z, fmaf(x0.w,wv.w, acc0[j]))));
      acc1[j] = fmaf(x1.x,wv.x, fmaf(x1.y,wv.y, fmaf(x1.z,wv.z, fmaf(x1.w,wv.w, acc1[j]))));
    }
  }
#pragma unroll
  for (int j = 0; j < 5; j++) {
    int c = cg + 8*j;
    if (c < 36) {
      DBC[(size_t)(row0 + 2*rg    ) * 36 + c] = acc0[j];
      DBC[(size_t)(row0 + 2*rg + 1) * 36 + c] = acc1[j];
    }
  }
}

// ---------------- scan pass1: per-chunk (prod a, h|h0=0) summaries ----------------
__global__ __launch_bounds__(128) void scan_pass1_k(
    const float* __restrict__ DBC_, const float* __restrict__ XI_,
    const float* __restrict__ dtw, const float* __restrict__ dtb,
    const float* __restrict__ alog,
    float* __restrict__ AP, float* __restrict__ HZ)
{
  int b  = blockIdx.x >> 6;   // / CHUNKS
  int ch = blockIdx.x & 63;
  int e  = threadIdx.x;
  float a[NS];
#pragma unroll
  for (int n = 0; n < NS; n++) a[n] = -__expf(alog[e*NS + n]);
  float4 w4 = *(const float4*)(dtw + e*4);
  float bias = dtb[e];
  float h[NS], ap[NS];
#pragma unroll
  for (int n = 0; n < NS; n++) { h[n] = 0.f; ap[n] = 1.f; }
  int l0 = ch * CHLEN;
  for (int t = 0; t < CHLEN; t++) {
    int bl = b * L_ + l0 + t;
    const float* dr = DBC_ + (size_t)bl * 36;
    float4 d4 = *(const float4*)dr;
    float pre = fmaf(d4.x,w4.x, fmaf(d4.y,w4.y, fmaf(d4.z,w4.z, fmaf(d4.w,w4.w, bias))));
    float ex = __expf(pre);
    float delta = (pre > 20.f) ? pre : __logf(1.f + ex);   // softplus
    float xi = XI_[(size_t)bl * ED_ + e];
    float dx = delta * xi;
    float4 b0 = *(const float4*)(dr + 4);
    float4 b1 = *(const float4*)(dr + 8);
    float4 b2 = *(const float4*)(dr + 12);
    float4 b3 = *(const float4*)(dr + 16);
    float Bv[NS] = {b0.x,b0.y,b0.z,b0.w, b1.x,b1.y,b1.z,b1.w,
                    b2.x,b2.y,b2.z,b2.w, b3.x,b3.y,b3.z,b3.w};
#pragma unroll
    for (int n = 0; n < NS; n++) {
      float da = __expf(delta * a[n]);
      ap[n] *= da;
      h[n] = fmaf(da, h[n], dx * Bv[n]);
    }
  }
  size_t base = ((size_t)(ch * B_ + b) * ED_ + e) * NS;
#pragma unroll
  for (int i = 0; i < 4; i++) {
    *(float4*)(AP + base + i*4) = make_float4(ap[4*i], ap[4*i+1], ap[4*i+2], ap[4*i+3]);
    *(float4*)(HZ + base + i*4) = make_float4(h[4*i],  h[4*i+1],  h[4*i+2],  h[4*i+3]);
  }
}

// ---------------- scan combine: sequential over chunk summaries ----------------
__global__ __launch_bounds__(256) void scan_combine_k(const float* __restrict__ AP,
    const float* __restrict__ HZ, float* __restrict__ HI)
{
  int t = blockIdx.x * 256 + threadIdx.x;   // B_*ED_*NS = 32768
  float h = 0.f;
  for (int c = 0; c < CHUNKS; c++) {
    size_t idx = (size_t)c * (B_*ED_*NS) + t;
    HI[idx] = h;
    h = fmaf(AP[idx], h, HZ[idx]);
  }
}

// ---------------- scan pass2: replay with h0, fuse C-dot + Dskip + silu(z) gate ----
__global__ __launch_bounds__(128) void scan_pass2_k(
    const float* __restrict__ DBC_, float* __restrict__ XI_,   // in: xi, out: y*silu(z)
    const float* __restrict__ XZ,
    const float* __restrict__ dtw, const float* __restrict__ dtb,
    const float* __restrict__ alog, const float* __restrict__ Dp_,
    const float* __restrict__ HI)
{
  int b  = blockIdx.x >> 6;
  int ch = blockIdx.x & 63;
  int e  = threadIdx.x;
  float a[NS];
#pragma unroll
  for (int n = 0; n < NS; n++) a[n] = -__expf(alog[e*NS + n]);
  float4 w4 = *(const float4*)(dtw + e*4);
  float bias = dtb[e];
  float Dp = Dp_[e];
  size_t sbase = ((size_t)(ch * B_ + b) * ED_ + e) * NS;
  float h[NS];
#pragma unroll
  for (int i = 0; i < 4; i++) {
    float4 v = *(const float4*)(HI + sbase + i*4);
    h[4*i] = v.x; h[4*i+1] = v.y; h[4*i+2] = v.z; h[4*i+3] = v.w;
  }
  int l0 = ch * CHLEN;
  for (int t = 0; t < CHLEN; t++) {
    int bl = b * L_ + l0 + t;
    const float* dr = DBC_ + (size_t)bl * 36;
    float4 d4 = *(const float4*)dr;
    float pre = fmaf(d4.x,w4.x, fmaf(d4.y,w4.y, fmaf(d4.z,w4.z, fmaf(d4.w,w4.w, bias))));
    float ex = __expf(pre);
    float delta = (pre > 20.f) ? pre : __logf(1.f + ex);
    float xi = XI_[(size_t)bl * ED_ + e];
    float dx = delta * xi;
    float4 b0 = *(const float4*)(dr + 4);
    float4 b1 = *(const float4*)(dr + 8);
    float4 b2 = *(const float4*)(dr + 12);
    float4 b3 = *(const float4*)(dr + 16);
    float4 c0 = *(const float4*)(dr + 20);
    float4 c1 = *(const float4*)(dr + 24);
    float4 c2 = *(const float4*)(dr + 28);
    float4 c3 = *(const float4*)(dr + 32);
    float Bv[NS] = {b0.x,b0.y,b0.z,b0.w, b1.x,b1.y,b1.z,b1.w,
                    b2.x,b2.y,b2.z,b2.w, b3.x,b3.y,b3.z,b3.w};
    float Cv[NS] = {c0.x,c0.y,c0.z,c0.w, c1.x,c1.y,c1.z,c1.w,
                    c2.x,c2.y,c2.z,c2.w, c3.x,c3.y,c3.z,c3.w};
    float y = 0.f;
#pragma unroll
    for (int n = 0; n < NS; n++) {
      float da = __expf(delta * a[n]);
      h[n] = fmaf(da, h[n], dx * Bv[n]);
      y = fmaf(h[n], Cv[n], y);
    }
    y = fmaf(Dp, xi, y);
    float z = XZ[(size_t)bl * 256 + 128 + e];
    float sz = z / (1.f + __expf(-z));
    XI_[(size_t)bl * ED_ + e] = y * sz;   // in-place: this thread just consumed xi[bl,e]
  }
}

// ---------------- GEMM3 + residual: xnew = xold + y @ out_w^T (M=BL,K=128,N=64) ---
__global__ __launch_bounds__(256) void gemm_out_k(const float* __restrict__ Y,
    const float* __restrict__ W, const float* __restrict__ XOLD, float* __restrict__ XNEW)
{
  __shared__ float4 sY[32][32];   // 32 rows x 128 K (16 KB)
  __shared__ float4 sW[32][64];   // [k4][c]        (32 KB)
  int tid = threadIdx.x;
  int row0 = blockIdx.x * 32;
  for (int i = tid; i < 32 * 32; i += 256) {
    int r = i >> 5, k4 = i & 31;
    sY[r][k4] = *(const float4*)(Y + (size_t)(row0 + r) * 128 + k4 * 4);
  }
  for (int i = tid; i < 64 * 32; i += 256) {
    int c = i >> 5, k4 = i & 31;
    sW[k4][c] = *(const float4*)(W + (size_t)c * 128 + k4 * 4);
  }
  __syncthreads();
  int r  = tid >> 3;   // 1 row each
  int cg = tid & 7;    // cols cg + 8j, j<8
  float acc[8];
#pragma unroll
  for (int j = 0; j < 8; j++) acc[j] = 0.f;
  for (int k4 = 0; k4 < 32; k4++) {
    float4 y4 = sY[r][k4];
#pragma unroll
    for (int j = 0; j < 8; j++) {
      float4 wv = sW[k4][cg + 8*j];
      acc[j] = fmaf(y4.x,wv.x, fmaf(y4.y,wv.y, fmaf(y4.z,wv.z, fmaf(y4.w,wv.w, acc[j]))));
    }
  }
#pragma unroll
  for (int j = 0; j < 8; j++) {
    int c = cg + 8*j;
    size_t idx = (size_t)(row0 + r) * 64 + c;
    XNEW[idx] = XOLD[idx] + acc[j];
  }
}

// ---------------- final head: out = x[:, -1, :] @ fc_w^T + fc_b ----------------
__global__ __launch_bounds__(256) void final_k(const float* __restrict__ X,
    const float* __restrict__ fcw, const float* __restrict__ fcb, float* __restrict__ out)
{
  int t = blockIdx.x * 256 + threadIdx.x;   // 1024
  int b = t >> 6, o = t & 63;
  const float* xrow = X + ((size_t)b * L_ + (L_ - 1)) * 64;
  const float* wrow = fcw + o * 64;
  float acc = fcb[o];
#pragma unroll
  for (int d = 0; d < 64; d++) acc = fmaf(xrow[d], wrow[d], acc);
  out[t] = acc;
}

extern "C" void kernel_launch(void* const* d_in, const int* in_sizes, int n_in,
                              void* d_out, int out_size, void* d_ws, size_t ws_size,
                              hipStream_t stream)
{
  const float* x_in   = (const float*)d_in[0];
  const float* norm_w = (const float*)d_in[1];
  const float* in_w   = (const float*)d_in[2];
  const float* conv_w = (const float*)d_in[3];
  const float* conv_b = (const float*)d_in[4];
  const float* xp_w   = (const float*)d_in[5];
  const float* dt_w   = (const float*)d_in[6];
  const float* dt_b   = (const float*)d_in[7];
  const float* A_log  = (const float*)d_in[8];
  const float* D_skip = (const float*)d_in[9];
  const float* out_w  = (const float*)d_in[10];
  const float* fc_w   = (const float*)d_in[11];
  const float* fc_b   = (const float*)d_in[12];
  float* out = (float*)d_out;

  // workspace layout (floats). Total = 22,151,168 floats = 88.6 MB.
  float* ws  = (float*)d_ws;
  float* X   = ws;                   // BL*64
  float* XN  = X   + (size_t)BL*64;  // BL*64   (aliased by APROD after gemm_in)
  float* XZ  = XN  + (size_t)BL*64;  // BL*256
  float* XI  = XZ  + (size_t)BL*256; // BL*128
  float* DBC = XI  + (size_t)BL*128; // BL*36
  float* HZ  = DBC + (size_t)BL*36;  // CHUNKS*B_*ED_*NS = 2,097,152
  float* HI  = HZ  + (size_t)CHUNKS*B_*ED_*NS;
  float* AP  = XN;                   // alias: XN dead once gemm_in has run

  for (int l = 0; l < NL_; l++) {
    const float* xsrc = (l == 0) ? x_in : X;
    rmsnorm_k   <<<BL/16, 256, 0, stream>>>(xsrc, norm_w + l*DM, XN);
    gemm_in_k   <<<dim3(BL/32, 2), 256, 0, stream>>>(XN, in_w + (size_t)l*2*ED_*DM, XZ);
    conv_silu_k <<<BL*ED_/256, 256, 0, stream>>>(XZ, conv_w + l*ED_*4, conv_b + l*ED_, XI);
    gemm_dbc_k  <<<BL/64, 256, 0, stream>>>(XI, xp_w + (size_t)l*36*ED_, DBC);
    scan_pass1_k<<<B_*CHUNKS, 128, 0, stream>>>(DBC, XI,
                    dt_w + l*ED_*RK, dt_b + l*ED_, A_log + l*ED_*NS, AP, HZ);
    scan_combine_k<<<(B_*ED_*NS)/256, 256, 0, stream>>>(AP, HZ, HI);
    scan_pass2_k<<<B_*CHUNKS, 128, 0, stream>>>(DBC, XI, XZ,
                    dt_w + l*ED_*RK, dt_b + l*ED_, A_log + l*ED_*NS, D_skip + l*ED_, HI);
    gemm_out_k  <<<BL/32, 256, 0, stream>>>(XI, out_w + (size_t)l*DM*ED_, xsrc, X);
  }
  final_k<<<4, 256, 0, stream>>>(X, fc_w, fc_b, out);
}

// Round 6
// 540.924 us; speedup vs baseline: 1.0328x; 1.0328x over previous
//
#include <hip/hip_runtime.h>
#include <math.h>

// MambaForecaster: B=16, L=2048, Dm=64, NL=4, ED=128, N=16, R=4, DC=4
#define B_   16
#define L_   2048
#define DM   64
#define NL_  4
#define ED_  128
#define NS   16
#define RK   4
#define BL   (B_*L_)          // 32768 rows
#define CHUNKS 128
#define CHLEN  (L_/CHUNKS)    // 16
#define SEQS   (B_*ED_*NS)    // 32768 sequences for the combine

// ---- GEMM1 + fused RMSNorm: xz = rmsnorm(x) @ in_w^T  (M=BL,K=64,N=256) ----
__global__ __launch_bounds__(256) void gemm_in_rms_k(const float* __restrict__ X,
    const float* __restrict__ nw, const float* __restrict__ W, float* __restrict__ XZ)
{
  __shared__ float4 sX[32][16];    // 32 rows x 64 K  (8 KB)
  __shared__ float4 sW[16][128];   // [k4][c]         (32 KB)
  int tid = threadIdx.x;
  int row0 = blockIdx.x * 32;
  const float* Wh = W + (size_t)blockIdx.y * 128 * 64;
  // stage X with on-the-fly rmsnorm: 16 consecutive lanes own one row
#pragma unroll
  for (int it = 0; it < 2; it++) {
    int i = tid + it * 256;
    int r = i >> 4, q = i & 15;
    float4 v = *(const float4*)(X + (size_t)(row0 + r) * 64 + q * 4);
    float ss = v.x*v.x + v.y*v.y + v.z*v.z + v.w*v.w;
    ss += __shfl_xor(ss, 1, 16);
    ss += __shfl_xor(ss, 2, 16);
    ss += __shfl_xor(ss, 4, 16);
    ss += __shfl_xor(ss, 8, 16);
    float sc = rsqrtf(ss * (1.0f/64.0f) + 1e-5f);
    float4 wv = *(const float4*)(nw + q * 4);
    float4 o;
    o.x = v.x*sc*wv.x; o.y = v.y*sc*wv.y; o.z = v.z*sc*wv.z; o.w = v.w*sc*wv.w;
    sX[r][q] = o;
  }
  for (int i = tid; i < 128 * 16; i += 256) {
    int c = i >> 4, k4 = i & 15;
    sW[k4][c] = *(const float4*)(Wh + (size_t)c * 64 + k4 * 4);
  }
  __syncthreads();
  int rg = tid >> 4;   // rows 2rg, 2rg+1
  int cg = tid & 15;   // cols cg + 16j, j<8
  float acc0[8], acc1[8];
#pragma unroll
  for (int j = 0; j < 8; j++) { acc0[j] = 0.f; acc1[j] = 0.f; }
  for (int k4 = 0; k4 < 16; k4++) {
    float4 x0 = sX[2*rg][k4];
    float4 x1 = sX[2*rg+1][k4];
#pragma unroll
    for (int j = 0; j < 8; j++) {
      float4 wv = sW[k4][cg + 16*j];
      acc0[j] = fmaf(x0.x,wv.x, fmaf(x0.y,wv.y, fmaf(x0.z,wv.z, fmaf(x0.w,wv.w, acc0[j]))));
      acc1[j] = fmaf(x1.x,wv.x, fmaf(x1.y,wv.y, fmaf(x1.z,wv.z, fmaf(x1.w,wv.w, acc1[j]))));
    }
  }
#pragma unroll
  for (int j = 0; j < 8; j++) {
    int c = blockIdx.y * 128 + cg + 16*j;
    XZ[(size_t)(row0 + 2*rg    ) * 256 + c] = acc0[j];
    XZ[(size_t)(row0 + 2*rg + 1) * 256 + c] = acc1[j];
  }
}

// ---- fused conv+silu+GEMM2: xi = silu(causal_conv(xz[:, :128])); dbc = xi @ xp_w^T
//      writes both XI (for scan) and DBC.  (M=BL rows of 64, K=128, N=36) ----
__global__ __launch_bounds__(256) void convdbc_k(const float* __restrict__ XZ,
    const float* __restrict__ cw, const float* __restrict__ cb,
    const float* __restrict__ W, float* __restrict__ XI, float* __restrict__ DBC)
{
  __shared__ float4 sX[64][32];   // 64 rows x 128 (32 KB) -- holds conv+silu output
  __shared__ float4 sW[32][40];   // [k4][f], padded 36->40 (20 KB)
  int tid = threadIdx.x;
  int row0 = blockIdx.x * 64;     // 64 rows, always within one batch (2048%64==0)
  int l0 = row0 & (L_ - 1);
  for (int i = tid; i < 64 * 32; i += 256) {
    int r = i >> 5, k4 = i & 31;
    int l = l0 + r;
    const float* base = XZ + (size_t)(row0 + r) * 256 + k4 * 4;
    float4 z4 = make_float4(0.f,0.f,0.f,0.f);
    float4 t3 = (l >= 3) ? *(const float4*)(base - 3*256) : z4;
    float4 t2 = (l >= 2) ? *(const float4*)(base - 2*256) : z4;
    float4 t1 = (l >= 1) ? *(const float4*)(base - 1*256) : z4;
    float4 t0 = *(const float4*)(base);
    float4 w0 = *(const float4*)(cw + (k4*4+0)*4);
    float4 w1 = *(const float4*)(cw + (k4*4+1)*4);
    float4 w2 = *(const float4*)(cw + (k4*4+2)*4);
    float4 w3 = *(const float4*)(cw + (k4*4+3)*4);
    float4 bb = *(const float4*)(cb + k4*4);
    float4 o;
    o.x = fmaf(t3.x,w0.x, fmaf(t2.x,w0.y, fmaf(t1.x,w0.z, fmaf(t0.x,w0.w, bb.x))));
    o.y = fmaf(t3.y,w1.x, fmaf(t2.y,w1.y, fmaf(t1.y,w1.z, fmaf(t0.y,w1.w, bb.y))));
    o.z = fmaf(t3.z,w2.x, fmaf(t2.z,w2.y, fmaf(t1.z,w2.z, fmaf(t0.z,w2.w, bb.z))));
    o.w = fmaf(t3.w,w3.x, fmaf(t2.w,w3.y, fmaf(t1.w,w3.z, fmaf(t0.w,w3.w, bb.w))));
    o.x = o.x / (1.f + __expf(-o.x));
    o.y = o.y / (1.f + __expf(-o.y));
    o.z = o.z / (1.f + __expf(-o.z));
    o.w = o.w / (1.f + __expf(-o.w));
    sX[r][k4] = o;
    *(float4*)(XI + (size_t)(row0 + r) * 128 + k4 * 4) = o;
  }
  for (int i = tid; i < 36 * 32; i += 256) {
    int f = i >> 5, k4 = i & 31;
    sW[k4][f] = *(const float4*)(W + (size_t)f * 128 + k4 * 4);
  }
  __syncthreads();
  int rg = tid >> 3;  // rows 2rg, 2rg+1
  int cg = tid & 7;   // cols cg + 8j, j<5 (valid if <36)
  float acc0[5], acc1[5];
#pragma unroll
  for (int j = 0; j < 5; j++) { acc0[j] = 0.f; acc1[j] = 0.f; }
  for (int k4 = 0; k4 < 32; k4++) {
    float4 x0 = sX[2*rg][k4];
    float4 x1 = sX[2*rg+1][k4];
#pragma unroll
    for (int j = 0; j < 5; j++) {
      float4 wv = sW[k4][cg + 8*j];
      acc0[j] = fmaf(x0.x,wv.x, fmaf(x0.y,wv.y, fmaf(x0.z,wv.z, fmaf(x0.w,wv.w, acc0[j]))));
      acc1[j] = fmaf(x1.x,wv.x, fmaf(x1.y,wv.y, fmaf(x1.z,wv.z, fmaf(x1.w,wv.w, acc1[j]))));
    }
  }
#pragma unroll
  for (int j = 0; j < 5; j++) {
    int c = cg + 8*j;
    if (c < 36) {
      DBC[(size_t)(row0 + 2*rg    ) * 36 + c] = acc0[j];
      DBC[(size_t)(row0 + 2*rg + 1) * 36 + c] = acc1[j];
    }
  }
}

// ---- scan pass1: per-chunk (prod a, h|h0=0) summaries.  layout [ch][b][e][n] ----
__global__ __launch_bounds__(128, 4) void scan_pass1_k(
    const float* __restrict__ DBC_, const float* __restrict__ XI_,
    const float* __restrict__ dtw, const float* __restrict__ dtb,
    const float* __restrict__ alog,
    float* __restrict__ AP, float* __restrict__ HZ)
{
  int b  = blockIdx.x >> 7;
  int ch = blockIdx.x & (CHUNKS - 1);
  int e  = threadIdx.x;
  float a[NS];
#pragma unroll
  for (int n = 0; n < NS; n++) a[n] = -__expf(alog[e*NS + n]);
  float4 w4 = *(const float4*)(dtw + e*4);
  float bias = dtb[e];
  float h[NS], ap[NS];
#pragma unroll
  for (int n = 0; n < NS; n++) { h[n] = 0.f; ap[n] = 1.f; }
  int l0 = ch * CHLEN;
  for (int t = 0; t < CHLEN; t++) {
    int bl = b * L_ + l0 + t;
    const float* dr = DBC_ + (size_t)bl * 36;
    float4 d4 = *(const float4*)dr;
    float pre = fmaf(d4.x,w4.x, fmaf(d4.y,w4.y, fmaf(d4.z,w4.z, fmaf(d4.w,w4.w, bias))));
    float ex = __expf(pre);
    float delta = (pre > 20.f) ? pre : __logf(1.f + ex);   // softplus
    float xi = XI_[(size_t)bl * ED_ + e];
    float dx = delta * xi;
    float4 b0 = *(const float4*)(dr + 4);
    float4 b1 = *(const float4*)(dr + 8);
    float4 b2 = *(const float4*)(dr + 12);
    float4 b3 = *(const float4*)(dr + 16);
    float Bv[NS] = {b0.x,b0.y,b0.z,b0.w, b1.x,b1.y,b1.z,b1.w,
                    b2.x,b2.y,b2.z,b2.w, b3.x,b3.y,b3.z,b3.w};
#pragma unroll
    for (int n = 0; n < NS; n++) {
      float da = __expf(delta * a[n]);
      ap[n] *= da;
      h[n] = fmaf(da, h[n], dx * Bv[n]);
    }
  }
  size_t base = ((size_t)(ch * B_ + b) * ED_ + e) * NS;   // == ch*SEQS + (b*ED+e)*NS
#pragma unroll
  for (int i = 0; i < 4; i++) {
    *(float4*)(AP + base + i*4) = make_float4(ap[4*i], ap[4*i+1], ap[4*i+2], ap[4*i+3]);
    *(float4*)(HZ + base + i*4) = make_float4(h[4*i],  h[4*i+1],  h[4*i+2],  h[4*i+3]);
  }
}

// ---- scan combine: wave-parallel scan over 128 chunk summaries per sequence ----
// AP/HZ/HI layout: [ch][t], t = (b*ED+e)*NS+n in [0,SEQS). Block: 32 sequences.
__global__ __launch_bounds__(256) void scan_combine_k(const float* __restrict__ AP,
    const float* __restrict__ HZ, float* __restrict__ HI)
{
  __shared__ float sA[CHUNKS * 33];
  __shared__ float sH[CHUNKS * 33];
  int tid = threadIdx.x;
  int t0 = blockIdx.x * 32;
  for (int i = tid; i < CHUNKS * 32; i += 256) {
    int ch = i >> 5, s = i & 31;
    sA[ch*33 + s] = AP[(size_t)ch * SEQS + t0 + s];
    sH[ch*33 + s] = HZ[(size_t)ch * SEQS + t0 + s];
  }
  __syncthreads();
  int lane = tid & 63;
  int wid = tid >> 6;          // 4 waves, 8 sequences each
  for (int j = 0; j < 8; j++) {
    int s = wid * 8 + j;
    // lane l owns chunk pair (2l, 2l+1)
    float a0 = sA[(2*lane)*33 + s],   h0 = sH[(2*lane)*33 + s];
    float a1 = sA[(2*lane+1)*33 + s], h1 = sH[(2*lane+1)*33 + s];
    float aL = a0 * a1;
    float hL = fmaf(a1, h0, h1);
#pragma unroll
    for (int off = 1; off < 64; off <<= 1) {
      float aP = __shfl_up(aL, off, 64);
      float hP = __shfl_up(hL, off, 64);
      if (lane >= off) { hL = fmaf(aL, hP, hL); aL = aP * aL; }
    }
    float hPrev = __shfl_up(hL, 1, 64);       // inclusive through pair l-1
    if (lane == 0) hPrev = 0.f;
    sA[(2*lane)*33 + s]   = hPrev;            // state entering chunk 2l
    sA[(2*lane+1)*33 + s] = fmaf(a0, hPrev, h0);  // entering chunk 2l+1
  }
  __syncthreads();
  for (int i = tid; i < CHUNKS * 32; i += 256) {
    int ch = i >> 5, s = i & 31;
    HI[(size_t)ch * SEQS + t0 + s] = sA[ch*33 + s];
  }
}

// ---- scan pass2: replay with h0, fuse C-dot + Dskip + silu(z) gate ----
__global__ __launch_bounds__(128, 4) void scan_pass2_k(
    const float* __restrict__ DBC_, float* __restrict__ XI_,
    const float* __restrict__ XZ,
    const float* __restrict__ dtw, const float* __restrict__ dtb,
    const float* __restrict__ alog, const float* __restrict__ Dp_,
    const float* __restrict__ HI)
{
  int b  = blockIdx.x >> 7;
  int ch = blockIdx.x & (CHUNKS - 1);
  int e  = threadIdx.x;
  float a[NS];
#pragma unroll
  for (int n = 0; n < NS; n++) a[n] = -__expf(alog[e*NS + n]);
  float4 w4 = *(const float4*)(dtw + e*4);
  float bias = dtb[e];
  float Dp = Dp_[e];
  size_t sbase = ((size_t)(ch * B_ + b) * ED_ + e) * NS;
  float h[NS];
#pragma unroll
  for (int i = 0; i < 4; i++) {
    float4 v = *(const float4*)(HI + sbase + i*4);
    h[4*i] = v.x; h[4*i+1] = v.y; h[4*i+2] = v.z; h[4*i+3] = v.w;
  }
  int l0 = ch * CHLEN;
  for (int t = 0; t < CHLEN; t++) {
    int bl = b * L_ + l0 + t;
    const float* dr = DBC_ + (size_t)bl * 36;
    float4 d4 = *(const float4*)dr;
    float pre = fmaf(d4.x,w4.x, fmaf(d4.y,w4.y, fmaf(d4.z,w4.z, fmaf(d4.w,w4.w, bias))));
    float ex = __expf(pre);
    float delta = (pre > 20.f) ? pre : __logf(1.f + ex);
    float xi = XI_[(size_t)bl * ED_ + e];
    float dx = delta * xi;
    float4 b0 = *(const float4*)(dr + 4);
    float4 b1 = *(const float4*)(dr + 8);
    float4 b2 = *(const float4*)(dr + 12);
    float4 b3 = *(const float4*)(dr + 16);
    float4 c0 = *(const float4*)(dr + 20);
    float4 c1 = *(const float4*)(dr + 24);
    float4 c2 = *(const float4*)(dr + 28);
    float4 c3 = *(const float4*)(dr + 32);
    float Bv[NS] = {b0.x,b0.y,b0.z,b0.w, b1.x,b1.y,b1.z,b1.w,
                    b2.x,b2.y,b2.z,b2.w, b3.x,b3.y,b3.z,b3.w};
    float Cv[NS] = {c0.x,c0.y,c0.z,c0.w, c1.x,c1.y,c1.z,c1.w,
                    c2.x,c2.y,c2.z,c2.w, c3.x,c3.y,c3.z,c3.w};
    float y = 0.f;
#pragma unroll
    for (int n = 0; n < NS; n++) {
      float da = __expf(delta * a[n]);
      h[n] = fmaf(da, h[n], dx * Bv[n]);
      y = fmaf(h[n], Cv[n], y);
    }
    y = fmaf(Dp, xi, y);
    float z = XZ[(size_t)bl * 256 + 128 + e];
    float sz = z / (1.f + __expf(-z));
    XI_[(size_t)bl * ED_ + e] = y * sz;   // in-place
  }
}

// ---- GEMM3 + residual: xnew = xold + y @ out_w^T (M=BL,K=128,N=64) ----
__global__ __launch_bounds__(256) void gemm_out_k(const float* __restrict__ Y,
    const float* __restrict__ W, const float* __restrict__ XOLD, float* __restrict__ XNEW)
{
  __shared__ float4 sY[32][32];   // 16 KB
  __shared__ float4 sW[32][64];   // 32 KB
  int tid = threadIdx.x;
  int row0 = blockIdx.x * 32;
  for (int i = tid; i < 32 * 32; i += 256) {
    int r = i >> 5, k4 = i & 31;
    sY[r][k4] = *(const float4*)(Y + (size_t)(row0 + r) * 128 + k4 * 4);
  }
  for (int i = tid; i < 64 * 32; i += 256) {
    int c = i >> 5, k4 = i & 31;
    sW[k4][c] = *(const float4*)(W + (size_t)c * 128 + k4 * 4);
  }
  __syncthreads();
  int r  = tid >> 3;
  int cg = tid & 7;
  float acc[8];
#pragma unroll
  for (int j = 0; j < 8; j++) acc[j] = 0.f;
  for (int k4 = 0; k4 < 32; k4++) {
    float4 y4 = sY[r][k4];
#pragma unroll
    for (int j = 0; j < 8; j++) {
      float4 wv = sW[k4][cg + 8*j];
      acc[j] = fmaf(y4.x,wv.x, fmaf(y4.y,wv.y, fmaf(y4.z,wv.z, fmaf(y4.w,wv.w, acc[j]))));
    }
  }
#pragma unroll
  for (int j = 0; j < 8; j++) {
    int c = cg + 8*j;
    size_t idx = (size_t)(row0 + r) * 64 + c;
    XNEW[idx] = XOLD[idx] + acc[j];
  }
}

// ---- final head ----
__global__ __launch_bounds__(256) void final_k(const float* __restrict__ X,
    const float* __restrict__ fcw, const float* __restrict__ fcb, float* __restrict__ out)
{
  int t = blockIdx.x * 256 + threadIdx.x;   // 1024
  int b = t >> 6, o = t & 63;
  const float* xrow = X + ((size_t)b * L_ + (L_ - 1)) * 64;
  const float* wrow = fcw + o * 64;
  float acc = fcb[o];
#pragma unroll
  for (int d = 0; d < 64; d++) acc = fmaf(xrow[d], wrow[d], acc);
  out[t] = acc;
}

extern "C" void kernel_launch(void* const* d_in, const int* in_sizes, int n_in,
                              void* d_out, int out_size, void* d_ws, size_t ws_size,
                              hipStream_t stream)
{
  const float* x_in   = (const float*)d_in[0];
  const float* norm_w = (const float*)d_in[1];
  const float* in_w   = (const float*)d_in[2];
  const float* conv_w = (const float*)d_in[3];
  const float* conv_b = (const float*)d_in[4];
  const float* xp_w   = (const float*)d_in[5];
  const float* dt_w   = (const float*)d_in[6];
  const float* dt_b   = (const float*)d_in[7];
  const float* A_log  = (const float*)d_in[8];
  const float* D_skip = (const float*)d_in[9];
  const float* out_w  = (const float*)d_in[10];
  const float* fc_w   = (const float*)d_in[11];
  const float* fc_b   = (const float*)d_in[12];
  float* out = (float*)d_out;

  // workspace (floats): X 2.1M | XZ 8.4M | XI 4.2M | DBC 1.2M | AP/HZ/HI 4.2M each
  // total ~116 MB (ws is ~268 MB per harness fill size)
  float* ws  = (float*)d_ws;
  float* X   = ws;                                  // BL*64
  float* XZ  = X   + (size_t)BL*64;                 // BL*256
  float* XI  = XZ  + (size_t)BL*256;                // BL*128
  float* DBC = XI  + (size_t)BL*128;                // BL*36
  float* AP  = DBC + (size_t)BL*36;                 // CHUNKS*SEQS
  float* HZ  = AP  + (size_t)CHUNKS*SEQS;
  float* HI  = HZ  + (size_t)CHUNKS*SEQS;

  for (int l = 0; l < NL_; l++) {
    const float* xsrc = (l == 0) ? x_in : X;
    gemm_in_rms_k<<<dim3(BL/32, 2), 256, 0, stream>>>(xsrc, norm_w + l*DM,
                    in_w + (size_t)l*2*ED_*DM, XZ);
    convdbc_k   <<<BL/64, 256, 0, stream>>>(XZ, conv_w + l*ED_*4, conv_b + l*ED_,
                    xp_w + (size_t)l*36*ED_, XI, DBC);
    scan_pass1_k<<<B_*CHUNKS, 128, 0, stream>>>(DBC, XI,
                    dt_w + l*ED_*RK, dt_b + l*ED_, A_log + l*ED_*NS, AP, HZ);
    scan_combine_k<<<SEQS/32, 256, 0, stream>>>(AP, HZ, HI);
    scan_pass2_k<<<B_*CHUNKS, 128, 0, stream>>>(DBC, XI, XZ,
                    dt_w + l*ED_*RK, dt_b + l*ED_, A_log + l*ED_*NS, D_skip + l*ED_, HI);
    gemm_out_k  <<<BL/32, 256, 0, stream>>>(XI, out_w + (size_t)l*DM*ED_, xsrc, X);
  }
  final_k<<<4, 256, 0, stream>>>(X, fc_w, fc_b, out);
}